// Round 6
// baseline (670.612 us; speedup 1.0000x reference)
//
#include <hip/hip_runtime.h>

#define D_IN 256
#define D_OUT 128
#define NEG_SLOPE 0.2
#define CAP 128   // per-row LDS coefficient cache in row_kernel
#define BROW 144  // LDS byte stride per B row (128 payload + 16 pad)

typedef __attribute__((ext_vector_type(8))) short s16x8;   // 8 bf16 (4 VGPRs)
typedef __attribute__((ext_vector_type(4))) float f32x4;   // MFMA C/D frag

__device__ __forceinline__ unsigned short f2bf(float f) {   // fp32 -> bf16 RNE
    unsigned u = __float_as_uint(f);
    u += 0x7FFFu + ((u >> 16) & 1u);
    return (unsigned short)(u >> 16);
}
__device__ __forceinline__ float bf2f(unsigned short h) {
    return __uint_as_float(((unsigned)h) << 16);
}

// ---------------------------------------------------------------------------
// Dispatch A: block 0          : wa[k] = W[k,:].a_src (fp64), wa[256+k] = .a_dst
//             blocks [1,129)   : W -> wth/wtl [n][k] bf16 split
//             blocks [129, ...): sharded (x4) histogram of src
// ---------------------------------------------------------------------------
__global__ __launch_bounds__(256) void prep_count(
    const float* __restrict__ W, const float* __restrict__ a,
    double* __restrict__ wa,
    unsigned short* __restrict__ wth, unsigned short* __restrict__ wtl,
    const int* __restrict__ src, int* __restrict__ counts4, int M, int E) {
    if (blockIdx.x == 0) {
        int k = threadIdx.x;            // 0..255
        double s = 0.0, d = 0.0;
        for (int n = 0; n < D_OUT; ++n) {
            double w = (double)W[k * D_OUT + n];
            s += w * (double)a[n];
            d += w * (double)a[D_OUT + n];
        }
        wa[k] = s;
        wa[D_IN + k] = d;
        return;
    }
    if (blockIdx.x <= 128) {
        int idx = (blockIdx.x - 1) * 256 + threadIdx.x;   // 0..32767
        int n = idx & 127;                                 // coalesced read
        int k = idx >> 7;
        float w = W[k * D_OUT + n];
        unsigned short h = f2bf(w);
        wth[(size_t)n * D_IN + k] = h;
        wtl[(size_t)n * D_IN + k] = f2bf(w - bf2f(h));
        return;
    }
    int* cnt = counts4 + (size_t)(threadIdx.x & 3) * M;   // shard by lane%4
    int bid  = blockIdx.x - 129;
    int base = (bid * 256 + (int)threadIdx.x) * 4;
    if (base + 4 <= E) {
        int4 s4 = *(const int4*)(src + base);
        atomicAdd(&cnt[s4.x], 1); atomicAdd(&cnt[s4.y], 1);
        atomicAdd(&cnt[s4.z], 1); atomicAdd(&cnt[s4.w], 1);
    } else {
        for (int i = base; i < E; ++i) atomicAdd(&cnt[src[i]], 1);
    }
}

// ---------------------------------------------------------------------------
// Dispatch B: single-block exclusive scan of the 4-sharded counts
// ---------------------------------------------------------------------------
__global__ __launch_bounds__(1024) void scan_kernel(
    const int* __restrict__ c4, int* __restrict__ rowptr,
    int* __restrict__ cursor, int M) {
    __shared__ int part[1024];
    int t = threadIdx.x;
    int chunk = (M + 1023) >> 10;
    int b = t * chunk, e = min(b + chunk, M);
    int s = 0;
    for (int i = b; i < e; ++i)
        s += c4[i] + c4[M + i] + c4[2 * M + i] + c4[3 * M + i];
    part[t] = s;
    __syncthreads();
    for (int off = 1; off < 1024; off <<= 1) {
        int v = (t >= off) ? part[t - off] : 0;
        __syncthreads();
        part[t] += v;
        __syncthreads();
    }
    int running = (t == 0) ? 0 : part[t - 1];
    for (int i = b; i < e; ++i) {
        int cnt = c4[i] + c4[M + i] + c4[2 * M + i] + c4[3 * M + i];
        rowptr[i] = running; cursor[i] = running; running += cnt;
    }
    if (t == 1023) rowptr[M] = part[1023];
}

// ---------------------------------------------------------------------------
// Dispatch C: split-bf16 MFMA GEMM, B staged in LDS per 32-wide K-tile.
// 64 rows/block (16/wave), fp32 m out, fused exact fp64 s/d = x.wa epilogue.
// A-frag: A[m=lane&15][k=(lane>>4)*8+j]  (direct global, 16 rows x 128 B)
// B-frag: ds_read_b128 from staged [n][k] tile, row stride 144 B
// C/D   : col = lane&15, row = (lane>>4)*4 + reg
// ---------------------------------------------------------------------------
__global__ __launch_bounds__(256) void gemm_mfma(
    const float* __restrict__ x,
    const unsigned short* __restrict__ wth, const unsigned short* __restrict__ wtl,
    const double* __restrict__ wa,
    float* __restrict__ m,
    double* __restrict__ svec, double* __restrict__ dvec, int M) {
    __shared__ __align__(16) unsigned char bsm[128 * BROW];   // 18.4 KB

    const int tid  = threadIdx.x;
    const int wave = tid >> 6;
    const int lane = tid & 63;
    const int c    = lane & 15;        // A row offset / B col / C col
    const int q    = lane >> 4;        // k quad
    const int r0   = blockIdx.x * 64 + wave * 16;
    const int arow  = r0 + c;
    const int arowc = (arow < M) ? arow : (M - 1);   // clamp; stores guarded

    // staging assignment: thread -> (row sn, half sd: 0=high,1=low), 64 B each
    const int sn = tid >> 1;
    const int sd = tid & 1;
    const unsigned short* sgl = (sd ? wtl : wth) + (size_t)sn * D_IN;
    unsigned char* sls = bsm + sn * BROW + sd * 64;

    f32x4 acc[8];
#pragma unroll
    for (int t = 0; t < 8; ++t) acc[t] = (f32x4){0.f, 0.f, 0.f, 0.f};
    double ps = 0.0, pd = 0.0;

    for (int kt = 0; kt < 8; ++kt) {
        const int kb0 = kt * 32;
        // stage B k-slice: 128 rows x (64 B high + 64 B low)
        float4 t0 = *(const float4*)(sgl + kb0);
        float4 t1 = *(const float4*)(sgl + kb0 + 8);
        float4 t2 = *(const float4*)(sgl + kb0 + 16);
        float4 t3 = *(const float4*)(sgl + kb0 + 24);
        // A frag load for this kt (independent of LDS, overlaps barrier)
        const int kb = kb0 + q * 8;
        const float* xp = x + (size_t)arowc * D_IN + kb;
        float4 a0 = *(const float4*)(xp);
        float4 a1 = *(const float4*)(xp + 4);
        *(float4*)(sls +  0) = t0;
        *(float4*)(sls + 16) = t1;
        *(float4*)(sls + 32) = t2;
        *(float4*)(sls + 48) = t3;
        __syncthreads();

        float av[8] = {a0.x, a0.y, a0.z, a0.w, a1.x, a1.y, a1.z, a1.w};
        // fused exact fp64 s/d partials: x . wa
#pragma unroll
        for (int j = 0; j < 8; ++j) {
            ps += (double)av[j] * wa[kb + j];
            pd += (double)av[j] * wa[D_IN + kb + j];
        }
        // bf16 split of A fragment
        s16x8 ah, al;
#pragma unroll
        for (int j = 0; j < 8; ++j) {
            unsigned short h = f2bf(av[j]);
            ah[j] = (short)h;
            al[j] = (short)f2bf(av[j] - bf2f(h));
        }
#pragma unroll
        for (int t = 0; t < 8; ++t) {
            const unsigned char* bp = bsm + (t * 16 + c) * BROW + q * 16;
            s16x8 bh = *(const s16x8*)(bp);
            s16x8 bl = *(const s16x8*)(bp + 64);
            acc[t] = __builtin_amdgcn_mfma_f32_16x16x32_bf16(al, bh, acc[t], 0, 0, 0);
            acc[t] = __builtin_amdgcn_mfma_f32_16x16x32_bf16(ah, bl, acc[t], 0, 0, 0);
            acc[t] = __builtin_amdgcn_mfma_f32_16x16x32_bf16(ah, bh, acc[t], 0, 0, 0);
        }
        __syncthreads();
    }

    // s/d: reduce across the 4 k-quads (lanes sharing c)
    ps += __shfl_xor(ps, 16); ps += __shfl_xor(ps, 32);
    pd += __shfl_xor(pd, 16); pd += __shfl_xor(pd, 32);
    if (q == 0 && arow < M) { svec[arow] = ps; dvec[arow] = pd; }

    // m store (fp32)
#pragma unroll
    for (int t = 0; t < 8; ++t) {
#pragma unroll
        for (int reg = 0; reg < 4; ++reg) {
            int r = r0 + q * 4 + reg;
            if (r < M) m[(size_t)r * D_OUT + t * 16 + c] = acc[t][reg];
        }
    }
}

// ---------------------------------------------------------------------------
// Dispatch D: fill CSR, packed {dst, nv} int2, one 8B scattered store/edge
// ---------------------------------------------------------------------------
__global__ __launch_bounds__(256) void fill_kernel(
    const int* __restrict__ src, const int* __restrict__ dst,
    const float* __restrict__ nvals, int* __restrict__ cursor,
    int2* __restrict__ edges, int E) {
    int base = (blockIdx.x * 256 + (int)threadIdx.x) * 4;
    if (base + 4 <= E) {
        int4   s4 = *(const int4*)(src + base);
        int4   d4 = *(const int4*)(dst + base);
        float4 n4 = *(const float4*)(nvals + base);
        int p;
        p = atomicAdd(&cursor[s4.x], 1); edges[p] = make_int2(d4.x, __float_as_int(n4.x));
        p = atomicAdd(&cursor[s4.y], 1); edges[p] = make_int2(d4.y, __float_as_int(n4.y));
        p = atomicAdd(&cursor[s4.z], 1); edges[p] = make_int2(d4.z, __float_as_int(n4.z));
        p = atomicAdd(&cursor[s4.w], 1); edges[p] = make_int2(d4.w, __float_as_int(n4.w));
    } else {
        for (int i = base; i < E; ++i) {
            int p = atomicAdd(&cursor[src[i]], 1);
            edges[p] = make_int2(dst[i], __float_as_int(nvals[i]));
        }
    }
}

// ---------------------------------------------------------------------------
// Dispatch E: one wave per row. Pass A: fp64 row_sum + cache {dst, nv*v} in
// LDS. Pass B: fp32 m gather (float2/lane) unroll 16. No atomics.
// ---------------------------------------------------------------------------
__global__ __launch_bounds__(256) void row_kernel(
    const int* __restrict__ rowptr, const int2* __restrict__ edges,
    const double* __restrict__ svec, const double* __restrict__ dvec,
    const float* __restrict__ m, float* __restrict__ out, int M) {
    __shared__ int   s_dst[4][CAP];
    __shared__ float s_c[4][CAP];
    int w    = threadIdx.x >> 6;
    int lane = threadIdx.x & 63;
    int r    = blockIdx.x * 4 + w;
    if (r >= M) return;
    int beg = rowptr[r], end = rowptr[r + 1], len = end - beg;
    double sr  = svec[r];
    double sum = 0.0;
    for (int j = lane; j < len; j += 64) {
        int2 ed = edges[beg + j];
        double v = sr + dvec[ed.x];
        v = (v > 0.0) ? v : v * NEG_SLOPE;
        sum += v;
        if (j < CAP) {
            s_dst[w][j] = ed.x;
            s_c[w][j]   = (float)((double)__int_as_float(ed.y) * v);
        }
    }
#pragma unroll
    for (int off = 32; off > 0; off >>= 1) sum += __shfl_xor(sum, off);
    float invf = (float)(1.0 / sum);
    __builtin_amdgcn_wave_barrier();   // order LDS writes (pass A) before reads

    float2 acc = make_float2(0.f, 0.f);
    int lim = len < CAP ? len : CAP;
    int j = 0;
    for (; j + 16 <= lim; j += 16) {
        float2 mv[16]; float c16[16];
#pragma unroll
        for (int k = 0; k < 16; ++k) {
            int d  = s_dst[w][j + k];
            c16[k] = s_c[w][j + k] * invf;
            mv[k]  = ((const float2*)(m + (size_t)d * D_OUT))[lane];
        }
#pragma unroll
        for (int k = 0; k < 16; ++k) {
            acc.x = fmaf(c16[k], mv[k].x, acc.x);
            acc.y = fmaf(c16[k], mv[k].y, acc.y);
        }
    }
    for (; j < lim; ++j) {
        int d = s_dst[w][j];
        float cc = s_c[w][j] * invf;
        float2 mv = ((const float2*)(m + (size_t)d * D_OUT))[lane];
        acc.x = fmaf(cc, mv.x, acc.x);
        acc.y = fmaf(cc, mv.y, acc.y);
    }
    for (; j < len; ++j) {   // overflow (len > CAP): recompute inline
        int2 ed = edges[beg + j];
        double v = sr + dvec[ed.x];
        v = (v > 0.0) ? v : v * NEG_SLOPE;
        float cc = (float)((double)__int_as_float(ed.y) * v) * invf;
        float2 mv = ((const float2*)(m + (size_t)ed.x * D_OUT))[lane];
        acc.x = fmaf(cc, mv.x, acc.x);
        acc.y = fmaf(cc, mv.y, acc.y);
    }
    ((float2*)(out + (size_t)r * D_OUT))[lane] = acc;
}

// ---------------------------------------------------------------------------
extern "C" void kernel_launch(void* const* d_in, const int* in_sizes, int n_in,
                              void* d_out, int out_size, void* d_ws, size_t ws_size,
                              hipStream_t stream) {
    const float* x     = (const float*)d_in[0];
    const float* W     = (const float*)d_in[1];
    const float* a     = (const float*)d_in[2];
    const float* nvals = (const float*)d_in[3];
    const int*   nsrc  = (const int*)d_in[4];
    const int*   ndst  = (const int*)d_in[5];
    const int M = in_sizes[0] / D_IN;   // 50000
    const int E = in_sizes[4];          // 1600000
    float* out = (float*)d_out;

    char* ws = (char*)d_ws;
    size_t off = 0;
    float*  m    = (float*)(ws + off);           off += (size_t)M * D_OUT * sizeof(float); // 25.6 MB
    unsigned short* wth = (unsigned short*)(ws + off); off += (size_t)D_OUT * D_IN * 2;    // 64 KB
    unsigned short* wtl = (unsigned short*)(ws + off); off += (size_t)D_OUT * D_IN * 2;    // 64 KB
    double* wa   = (double*)(ws + off);          off += (size_t)2 * D_IN * sizeof(double); // 4 KB
    double* svec = (double*)(ws + off);          off += (size_t)M * sizeof(double);
    double* dvec = (double*)(ws + off);          off += (size_t)M * sizeof(double);
    int*    counts4 = (int*)(ws + off); off += ((size_t)4 * M * sizeof(int) + 15) & ~15ull; // 800 KB
    int*    rowptr  = (int*)(ws + off); off += ((size_t)(M + 1) * sizeof(int) + 15) & ~15ull;
    int*    cursor  = (int*)(ws + off); off += ((size_t)M * sizeof(int) + 15) & ~15ull;
    int2*   edges   = (int2*)(ws + off); off += (size_t)E * sizeof(int2);                   // 12.8 MB

    hipMemsetAsync(counts4, 0, (size_t)4 * M * sizeof(int), stream);

    const int countBlocks = (E + 1023) / 1024;   // 1563
    const int gemmBlocks  = (M + 63) / 64;       // 782

    prep_count<<<129 + countBlocks, 256, 0, stream>>>(W, a, wa, wth, wtl, nsrc, counts4, M, E);
    scan_kernel<<<1, 1024, 0, stream>>>(counts4, rowptr, cursor, M);
    gemm_mfma<<<gemmBlocks, 256, 0, stream>>>(x, wth, wtl, wa, m, svec, dvec, M);
    fill_kernel<<<countBlocks, 256, 0, stream>>>(nsrc, ndst, nvals, cursor, edges, E);
    row_kernel<<<(M + 3) / 4, 256, 0, stream>>>(rowptr, edges, svec, dvec, m, out, M);
}

// Round 7
// 432.593 us; speedup vs baseline: 1.5502x; 1.5502x over previous
//
#include <hip/hip_runtime.h>

#define D_IN 256
#define D_OUT 128
#define NEG_SLOPE 0.2
#define CAP 128   // per-row LDS coefficient cache in row_kernel
#define BROW 144  // LDS byte stride per B row (128 payload + 16 pad)

typedef __attribute__((ext_vector_type(8))) short s16x8;   // 8 bf16 (4 VGPRs)
typedef __attribute__((ext_vector_type(4))) float f32x4;   // MFMA C/D frag

__device__ __forceinline__ unsigned short f2bf(float f) {   // fp32 -> bf16 RNE
    unsigned u = __float_as_uint(f);
    u += 0x7FFFu + ((u >> 16) & 1u);
    return (unsigned short)(u >> 16);
}
__device__ __forceinline__ float bf2f(unsigned short h) {
    return __uint_as_float(((unsigned)h) << 16);
}

// ---------------------------------------------------------------------------
// Dispatch A: block 0          : wa[k] = W[k,:].a_src (fp64), wa[256+k] = .a_dst
//             blocks [1,129)   : W -> wth/wtl [n][k] bf16 split
//             blocks [129, ...): sharded (x4) histogram of src
// ---------------------------------------------------------------------------
__global__ __launch_bounds__(256) void prep_count(
    const float* __restrict__ W, const float* __restrict__ a,
    double* __restrict__ wa,
    unsigned short* __restrict__ wth, unsigned short* __restrict__ wtl,
    const int* __restrict__ src, int* __restrict__ counts4, int M, int E) {
    if (blockIdx.x == 0) {
        int k = threadIdx.x;            // 0..255
        double s = 0.0, d = 0.0;
        for (int n = 0; n < D_OUT; ++n) {
            double w = (double)W[k * D_OUT + n];
            s += w * (double)a[n];
            d += w * (double)a[D_OUT + n];
        }
        wa[k] = s;
        wa[D_IN + k] = d;
        return;
    }
    if (blockIdx.x <= 128) {
        int idx = (blockIdx.x - 1) * 256 + threadIdx.x;   // 0..32767
        int n = idx & 127;                                 // coalesced read
        int k = idx >> 7;
        float w = W[k * D_OUT + n];
        unsigned short h = f2bf(w);
        wth[(size_t)n * D_IN + k] = h;
        wtl[(size_t)n * D_IN + k] = f2bf(w - bf2f(h));
        return;
    }
    int* cnt = counts4 + (size_t)(threadIdx.x & 3) * M;   // shard by lane%4
    int bid  = blockIdx.x - 129;
    int base = (bid * 256 + (int)threadIdx.x) * 4;
    if (base + 4 <= E) {
        int4 s4 = *(const int4*)(src + base);
        atomicAdd(&cnt[s4.x], 1); atomicAdd(&cnt[s4.y], 1);
        atomicAdd(&cnt[s4.z], 1); atomicAdd(&cnt[s4.w], 1);
    } else {
        for (int i = base; i < E; ++i) atomicAdd(&cnt[src[i]], 1);
    }
}

// ---------------------------------------------------------------------------
// Hierarchical scan: scan1 (per-block sums) -> scan2 (scan of block sums)
//                    -> scan3 (block-local scan + offset, rowptr + cursor4)
// ---------------------------------------------------------------------------
__global__ __launch_bounds__(256) void scan1(
    const int* __restrict__ c4, int* __restrict__ bsum, int M) {
    __shared__ int red[256];
    int i = blockIdx.x * 256 + threadIdx.x;
    int tot = 0;
    if (i < M) tot = c4[i] + c4[M + i] + c4[2 * M + i] + c4[3 * M + i];
    red[threadIdx.x] = tot;
    __syncthreads();
    for (int off = 128; off > 0; off >>= 1) {
        if ((int)threadIdx.x < off) red[threadIdx.x] += red[threadIdx.x + off];
        __syncthreads();
    }
    if (threadIdx.x == 0) bsum[blockIdx.x] = red[0];
}

__global__ __launch_bounds__(256) void scan2(
    const int* __restrict__ bsum, int* __restrict__ boff,
    int* __restrict__ rowptr, int NB, int M) {
    __shared__ int part[256];
    int t = threadIdx.x;
    int v = (t < NB) ? bsum[t] : 0;
    part[t] = v;
    __syncthreads();
    for (int off = 1; off < 256; off <<= 1) {
        int u = (t >= off) ? part[t - off] : 0;
        __syncthreads();
        part[t] += u;
        __syncthreads();
    }
    if (t < NB) boff[t] = part[t] - v;          // exclusive
    if (t == NB - 1) rowptr[M] = part[t];       // total = E
}

__global__ __launch_bounds__(256) void scan3(
    const int* __restrict__ c4, const int* __restrict__ boff,
    int* __restrict__ rowptr, int* __restrict__ cursor4, int M) {
    __shared__ int part[256];
    int t = threadIdx.x;
    int i = blockIdx.x * 256 + t;
    int c0 = 0, c1 = 0, c2 = 0, c3 = 0;
    if (i < M) {
        c0 = c4[i]; c1 = c4[M + i]; c2 = c4[2 * M + i]; c3 = c4[3 * M + i];
    }
    int tot = c0 + c1 + c2 + c3;
    part[t] = tot;
    __syncthreads();
    for (int off = 1; off < 256; off <<= 1) {
        int u = (t >= off) ? part[t - off] : 0;
        __syncthreads();
        part[t] += u;
        __syncthreads();
    }
    if (i < M) {
        int base = boff[blockIdx.x] + part[t] - tot;   // exclusive within block
        rowptr[i] = base;
        cursor4[i]         = base;
        cursor4[M + i]     = base + c0;
        cursor4[2 * M + i] = base + c0 + c1;
        cursor4[3 * M + i] = base + c0 + c1 + c2;
    }
}

// ---------------------------------------------------------------------------
// Dispatch C: split-bf16 MFMA GEMM, B staged in LDS per 32-wide K-tile.
// 64 rows/block (16/wave), fp32 m out, fused exact fp64 s/d = x.wa epilogue.
// ---------------------------------------------------------------------------
__global__ __launch_bounds__(256) void gemm_mfma(
    const float* __restrict__ x,
    const unsigned short* __restrict__ wth, const unsigned short* __restrict__ wtl,
    const double* __restrict__ wa,
    float* __restrict__ m,
    double* __restrict__ svec, double* __restrict__ dvec, int M) {
    __shared__ __align__(16) unsigned char bsm[128 * BROW];   // 18.4 KB

    const int tid  = threadIdx.x;
    const int wave = tid >> 6;
    const int lane = tid & 63;
    const int c    = lane & 15;        // A row offset / B col / C col
    const int q    = lane >> 4;        // k quad
    const int r0   = blockIdx.x * 64 + wave * 16;
    const int arow  = r0 + c;
    const int arowc = (arow < M) ? arow : (M - 1);   // clamp; stores guarded

    const int sn = tid >> 1;
    const int sd = tid & 1;
    const unsigned short* sgl = (sd ? wtl : wth) + (size_t)sn * D_IN;
    unsigned char* sls = bsm + sn * BROW + sd * 64;

    f32x4 acc[8];
#pragma unroll
    for (int t = 0; t < 8; ++t) acc[t] = (f32x4){0.f, 0.f, 0.f, 0.f};
    double ps = 0.0, pd = 0.0;

    for (int kt = 0; kt < 8; ++kt) {
        const int kb0 = kt * 32;
        float4 t0 = *(const float4*)(sgl + kb0);
        float4 t1 = *(const float4*)(sgl + kb0 + 8);
        float4 t2 = *(const float4*)(sgl + kb0 + 16);
        float4 t3 = *(const float4*)(sgl + kb0 + 24);
        const int kb = kb0 + q * 8;
        const float* xp = x + (size_t)arowc * D_IN + kb;
        float4 a0 = *(const float4*)(xp);
        float4 a1 = *(const float4*)(xp + 4);
        *(float4*)(sls +  0) = t0;
        *(float4*)(sls + 16) = t1;
        *(float4*)(sls + 32) = t2;
        *(float4*)(sls + 48) = t3;
        __syncthreads();

        float av[8] = {a0.x, a0.y, a0.z, a0.w, a1.x, a1.y, a1.z, a1.w};
#pragma unroll
        for (int j = 0; j < 8; ++j) {
            ps += (double)av[j] * wa[kb + j];
            pd += (double)av[j] * wa[D_IN + kb + j];
        }
        s16x8 ah, al;
#pragma unroll
        for (int j = 0; j < 8; ++j) {
            unsigned short h = f2bf(av[j]);
            ah[j] = (short)h;
            al[j] = (short)f2bf(av[j] - bf2f(h));
        }
#pragma unroll
        for (int t = 0; t < 8; ++t) {
            const unsigned char* bp = bsm + (t * 16 + c) * BROW + q * 16;
            s16x8 bh = *(const s16x8*)(bp);
            s16x8 bl = *(const s16x8*)(bp + 64);
            acc[t] = __builtin_amdgcn_mfma_f32_16x16x32_bf16(al, bh, acc[t], 0, 0, 0);
            acc[t] = __builtin_amdgcn_mfma_f32_16x16x32_bf16(ah, bl, acc[t], 0, 0, 0);
            acc[t] = __builtin_amdgcn_mfma_f32_16x16x32_bf16(ah, bh, acc[t], 0, 0, 0);
        }
        __syncthreads();
    }

    ps += __shfl_xor(ps, 16); ps += __shfl_xor(ps, 32);
    pd += __shfl_xor(pd, 16); pd += __shfl_xor(pd, 32);
    if (q == 0 && arow < M) { svec[arow] = ps; dvec[arow] = pd; }

#pragma unroll
    for (int t = 0; t < 8; ++t) {
#pragma unroll
        for (int reg = 0; reg < 4; ++reg) {
            int r = r0 + q * 4 + reg;
            if (r < M) m[(size_t)r * D_OUT + t * 16 + c] = acc[t][reg];
        }
    }
}

// ---------------------------------------------------------------------------
// Dispatch D: fill CSR from 4-sharded cursors (shard = tid&3, matching the
// histogram's edge->thread mapping exactly). One 8B scattered store/edge.
// ---------------------------------------------------------------------------
__global__ __launch_bounds__(256) void fill_kernel(
    const int* __restrict__ src, const int* __restrict__ dst,
    const float* __restrict__ nvals, int* __restrict__ cursor4,
    int2* __restrict__ edges, int M, int E) {
    int* cur = cursor4 + (size_t)(threadIdx.x & 3) * M;
    int base = (blockIdx.x * 256 + (int)threadIdx.x) * 4;
    if (base + 4 <= E) {
        int4   s4 = *(const int4*)(src + base);
        int4   d4 = *(const int4*)(dst + base);
        float4 n4 = *(const float4*)(nvals + base);
        int p;
        p = atomicAdd(&cur[s4.x], 1); edges[p] = make_int2(d4.x, __float_as_int(n4.x));
        p = atomicAdd(&cur[s4.y], 1); edges[p] = make_int2(d4.y, __float_as_int(n4.y));
        p = atomicAdd(&cur[s4.z], 1); edges[p] = make_int2(d4.z, __float_as_int(n4.z));
        p = atomicAdd(&cur[s4.w], 1); edges[p] = make_int2(d4.w, __float_as_int(n4.w));
    } else {
        for (int i = base; i < E; ++i) {
            int p = atomicAdd(&cur[src[i]], 1);
            edges[p] = make_int2(dst[i], __float_as_int(nvals[i]));
        }
    }
}

// ---------------------------------------------------------------------------
// Dispatch E: one wave per row. Pass A: fp64 row_sum + cache {dst, nv*v} in
// LDS. Pass B: fp32 m gather (float2/lane) unroll 16. No atomics.
// ---------------------------------------------------------------------------
__global__ __launch_bounds__(256) void row_kernel(
    const int* __restrict__ rowptr, const int2* __restrict__ edges,
    const double* __restrict__ svec, const double* __restrict__ dvec,
    const float* __restrict__ m, float* __restrict__ out, int M) {
    __shared__ int   s_dst[4][CAP];
    __shared__ float s_c[4][CAP];
    int w    = threadIdx.x >> 6;
    int lane = threadIdx.x & 63;
    int r    = blockIdx.x * 4 + w;
    if (r >= M) return;
    int beg = rowptr[r], end = rowptr[r + 1], len = end - beg;
    double sr  = svec[r];
    double sum = 0.0;
    for (int j = lane; j < len; j += 64) {
        int2 ed = edges[beg + j];
        double v = sr + dvec[ed.x];
        v = (v > 0.0) ? v : v * NEG_SLOPE;
        sum += v;
        if (j < CAP) {
            s_dst[w][j] = ed.x;
            s_c[w][j]   = (float)((double)__int_as_float(ed.y) * v);
        }
    }
#pragma unroll
    for (int off = 32; off > 0; off >>= 1) sum += __shfl_xor(sum, off);
    float invf = (float)(1.0 / sum);
    __builtin_amdgcn_wave_barrier();   // order LDS writes (pass A) before reads

    float2 acc = make_float2(0.f, 0.f);
    int lim = len < CAP ? len : CAP;
    int j = 0;
    for (; j + 16 <= lim; j += 16) {
        float2 mv[16]; float c16[16];
#pragma unroll
        for (int k = 0; k < 16; ++k) {
            int d  = s_dst[w][j + k];
            c16[k] = s_c[w][j + k] * invf;
            mv[k]  = ((const float2*)(m + (size_t)d * D_OUT))[lane];
        }
#pragma unroll
        for (int k = 0; k < 16; ++k) {
            acc.x = fmaf(c16[k], mv[k].x, acc.x);
            acc.y = fmaf(c16[k], mv[k].y, acc.y);
        }
    }
    for (; j < lim; ++j) {
        int d = s_dst[w][j];
        float cc = s_c[w][j] * invf;
        float2 mv = ((const float2*)(m + (size_t)d * D_OUT))[lane];
        acc.x = fmaf(cc, mv.x, acc.x);
        acc.y = fmaf(cc, mv.y, acc.y);
    }
    for (; j < len; ++j) {   // overflow (len > CAP): recompute inline
        int2 ed = edges[beg + j];
        double v = sr + dvec[ed.x];
        v = (v > 0.0) ? v : v * NEG_SLOPE;
        float cc = (float)((double)__int_as_float(ed.y) * v) * invf;
        float2 mv = ((const float2*)(m + (size_t)ed.x * D_OUT))[lane];
        acc.x = fmaf(cc, mv.x, acc.x);
        acc.y = fmaf(cc, mv.y, acc.y);
    }
    ((float2*)(out + (size_t)r * D_OUT))[lane] = acc;
}

// ---------------------------------------------------------------------------
extern "C" void kernel_launch(void* const* d_in, const int* in_sizes, int n_in,
                              void* d_out, int out_size, void* d_ws, size_t ws_size,
                              hipStream_t stream) {
    const float* x     = (const float*)d_in[0];
    const float* W     = (const float*)d_in[1];
    const float* a     = (const float*)d_in[2];
    const float* nvals = (const float*)d_in[3];
    const int*   nsrc  = (const int*)d_in[4];
    const int*   ndst  = (const int*)d_in[5];
    const int M = in_sizes[0] / D_IN;   // 50000
    const int E = in_sizes[4];          // 1600000
    float* out = (float*)d_out;

    char* ws = (char*)d_ws;
    size_t off = 0;
    float*  m    = (float*)(ws + off);           off += (size_t)M * D_OUT * sizeof(float); // 25.6 MB
    unsigned short* wth = (unsigned short*)(ws + off); off += (size_t)D_OUT * D_IN * 2;    // 64 KB
    unsigned short* wtl = (unsigned short*)(ws + off); off += (size_t)D_OUT * D_IN * 2;    // 64 KB
    double* wa   = (double*)(ws + off);          off += (size_t)2 * D_IN * sizeof(double); // 4 KB
    double* svec = (double*)(ws + off);          off += (size_t)M * sizeof(double);
    double* dvec = (double*)(ws + off);          off += (size_t)M * sizeof(double);
    int*    counts4 = (int*)(ws + off); off += ((size_t)4 * M * sizeof(int) + 15) & ~15ull; // 800 KB
    int*    cursor4 = (int*)(ws + off); off += ((size_t)4 * M * sizeof(int) + 15) & ~15ull; // 800 KB
    int*    rowptr  = (int*)(ws + off); off += ((size_t)(M + 1) * sizeof(int) + 15) & ~15ull;
    int*    bsum    = (int*)(ws + off); off += (256 * sizeof(int) + 15) & ~15ull;
    int*    boff    = (int*)(ws + off); off += (256 * sizeof(int) + 15) & ~15ull;
    int2*   edges   = (int2*)(ws + off); off += (size_t)E * sizeof(int2);                   // 12.8 MB

    hipMemsetAsync(counts4, 0, (size_t)4 * M * sizeof(int), stream);

    const int countBlocks = (E + 1023) / 1024;   // 1563
    const int gemmBlocks  = (M + 63) / 64;       // 782
    const int NB          = (M + 255) / 256;     // 196

    prep_count<<<129 + countBlocks, 256, 0, stream>>>(W, a, wa, wth, wtl, nsrc, counts4, M, E);
    scan1<<<NB, 256, 0, stream>>>(counts4, bsum, M);
    scan2<<<1, 256, 0, stream>>>(bsum, boff, rowptr, NB, M);
    scan3<<<NB, 256, 0, stream>>>(counts4, boff, rowptr, cursor4, M);
    gemm_mfma<<<gemmBlocks, 256, 0, stream>>>(x, wth, wtl, wa, m, svec, dvec, M);
    fill_kernel<<<countBlocks, 256, 0, stream>>>(nsrc, ndst, nvals, cursor4, edges, M, E);
    row_kernel<<<(M + 3) / 4, 256, 0, stream>>>(rowptr, edges, svec, dvec, m, out, M);
}

// Round 8
// 363.573 us; speedup vs baseline: 1.8445x; 1.1898x over previous
//
#include <hip/hip_runtime.h>

#define D_IN 256
#define D_OUT 128
#define NEG_SLOPE 0.2
#define CAP 128   // per-row LDS coefficient cache in row_kernel
#define BROW 144  // LDS byte stride per B row (128 payload + 16 pad)

typedef __attribute__((ext_vector_type(8))) short s16x8;   // 8 bf16 (4 VGPRs)
typedef __attribute__((ext_vector_type(4))) float f32x4;   // MFMA C/D frag

__device__ __forceinline__ unsigned short f2bf(float f) {   // fp32 -> bf16 RNE
    unsigned u = __float_as_uint(f);
    u += 0x7FFFu + ((u >> 16) & 1u);
    return (unsigned short)(u >> 16);
}
__device__ __forceinline__ float bf2f(unsigned short h) {
    return __uint_as_float(((unsigned)h) << 16);
}

// ---------------------------------------------------------------------------
// Dispatch A: block 0          : wa[k] = W[k,:].a_src (fp64), wa[256+k] = .a_dst
//             blocks [1,129)   : W -> wth/wtl [n][k] bf16 split
//             blocks [129, ...): sharded (x4) histogram of src + rank store
// ---------------------------------------------------------------------------
__global__ __launch_bounds__(256) void prep_count(
    const float* __restrict__ W, const float* __restrict__ a,
    double* __restrict__ wa,
    unsigned short* __restrict__ wth, unsigned short* __restrict__ wtl,
    const int* __restrict__ src, int* __restrict__ counts4,
    int* __restrict__ rank, int M, int E) {
    if (blockIdx.x == 0) {
        int k = threadIdx.x;            // 0..255
        double s = 0.0, d = 0.0;
        for (int n = 0; n < D_OUT; ++n) {
            double w = (double)W[k * D_OUT + n];
            s += w * (double)a[n];
            d += w * (double)a[D_OUT + n];
        }
        wa[k] = s;
        wa[D_IN + k] = d;
        return;
    }
    if (blockIdx.x <= 128) {
        int idx = (blockIdx.x - 1) * 256 + threadIdx.x;   // 0..32767
        int n = idx & 127;                                 // coalesced read
        int k = idx >> 7;
        float w = W[k * D_OUT + n];
        unsigned short h = f2bf(w);
        wth[(size_t)n * D_IN + k] = h;
        wtl[(size_t)n * D_IN + k] = f2bf(w - bf2f(h));
        return;
    }
    int* cnt = counts4 + (size_t)(threadIdx.x & 3) * M;   // shard by tid%4
    int bid  = blockIdx.x - 129;
    int base = (bid * 256 + (int)threadIdx.x) * 4;
    if (base + 4 <= E) {
        int4 s4 = *(const int4*)(src + base);
        int4 r4;
        r4.x = atomicAdd(&cnt[s4.x], 1);
        r4.y = atomicAdd(&cnt[s4.y], 1);
        r4.z = atomicAdd(&cnt[s4.z], 1);
        r4.w = atomicAdd(&cnt[s4.w], 1);
        *(int4*)(rank + base) = r4;
    } else {
        for (int i = base; i < E; ++i) rank[i] = atomicAdd(&cnt[src[i]], 1);
    }
}

// ---------------------------------------------------------------------------
// Hierarchical scan: scan1 (per-block sums) -> scan2 (scan of block sums)
//                    -> scan3 (block-local scan + offset, rowptr + base4)
// ---------------------------------------------------------------------------
__global__ __launch_bounds__(256) void scan1(
    const int* __restrict__ c4, int* __restrict__ bsum, int M) {
    __shared__ int red[256];
    int i = blockIdx.x * 256 + threadIdx.x;
    int tot = 0;
    if (i < M) tot = c4[i] + c4[M + i] + c4[2 * M + i] + c4[3 * M + i];
    red[threadIdx.x] = tot;
    __syncthreads();
    for (int off = 128; off > 0; off >>= 1) {
        if ((int)threadIdx.x < off) red[threadIdx.x] += red[threadIdx.x + off];
        __syncthreads();
    }
    if (threadIdx.x == 0) bsum[blockIdx.x] = red[0];
}

__global__ __launch_bounds__(256) void scan2(
    const int* __restrict__ bsum, int* __restrict__ boff,
    int* __restrict__ rowptr, int NB, int M) {
    __shared__ int part[256];
    int t = threadIdx.x;
    int v = (t < NB) ? bsum[t] : 0;
    part[t] = v;
    __syncthreads();
    for (int off = 1; off < 256; off <<= 1) {
        int u = (t >= off) ? part[t - off] : 0;
        __syncthreads();
        part[t] += u;
        __syncthreads();
    }
    if (t < NB) boff[t] = part[t] - v;          // exclusive
    if (t == NB - 1) rowptr[M] = part[t];       // total = E
}

__global__ __launch_bounds__(256) void scan3(
    const int* __restrict__ c4, const int* __restrict__ boff,
    int* __restrict__ rowptr, int* __restrict__ base4, int M) {
    __shared__ int part[256];
    int t = threadIdx.x;
    int i = blockIdx.x * 256 + t;
    int c0 = 0, c1 = 0, c2 = 0, c3 = 0;
    if (i < M) {
        c0 = c4[i]; c1 = c4[M + i]; c2 = c4[2 * M + i]; c3 = c4[3 * M + i];
    }
    int tot = c0 + c1 + c2 + c3;
    part[t] = tot;
    __syncthreads();
    for (int off = 1; off < 256; off <<= 1) {
        int u = (t >= off) ? part[t - off] : 0;
        __syncthreads();
        part[t] += u;
        __syncthreads();
    }
    if (i < M) {
        int base = boff[blockIdx.x] + part[t] - tot;   // exclusive within block
        rowptr[i] = base;
        base4[i]         = base;
        base4[M + i]     = base + c0;
        base4[2 * M + i] = base + c0 + c1;
        base4[3 * M + i] = base + c0 + c1 + c2;
    }
}

// ---------------------------------------------------------------------------
// Dispatch C: split-bf16 MFMA GEMM, B staged in LDS per 32-wide K-tile.
// 64 rows/block (16/wave), fp32 m out, fused exact fp64 s/d = x.wa epilogue.
// ---------------------------------------------------------------------------
__global__ __launch_bounds__(256) void gemm_mfma(
    const float* __restrict__ x,
    const unsigned short* __restrict__ wth, const unsigned short* __restrict__ wtl,
    const double* __restrict__ wa,
    float* __restrict__ m,
    double* __restrict__ svec, double* __restrict__ dvec, int M) {
    __shared__ __align__(16) unsigned char bsm[128 * BROW];   // 18.4 KB

    const int tid  = threadIdx.x;
    const int wave = tid >> 6;
    const int lane = tid & 63;
    const int c    = lane & 15;        // A row offset / B col / C col
    const int q    = lane >> 4;        // k quad
    const int r0   = blockIdx.x * 64 + wave * 16;
    const int arow  = r0 + c;
    const int arowc = (arow < M) ? arow : (M - 1);   // clamp; stores guarded

    const int sn = tid >> 1;
    const int sd = tid & 1;
    const unsigned short* sgl = (sd ? wtl : wth) + (size_t)sn * D_IN;
    unsigned char* sls = bsm + sn * BROW + sd * 64;

    f32x4 acc[8];
#pragma unroll
    for (int t = 0; t < 8; ++t) acc[t] = (f32x4){0.f, 0.f, 0.f, 0.f};
    double ps = 0.0, pd = 0.0;

    for (int kt = 0; kt < 8; ++kt) {
        const int kb0 = kt * 32;
        float4 t0 = *(const float4*)(sgl + kb0);
        float4 t1 = *(const float4*)(sgl + kb0 + 8);
        float4 t2 = *(const float4*)(sgl + kb0 + 16);
        float4 t3 = *(const float4*)(sgl + kb0 + 24);
        const int kb = kb0 + q * 8;
        const float* xp = x + (size_t)arowc * D_IN + kb;
        float4 a0 = *(const float4*)(xp);
        float4 a1 = *(const float4*)(xp + 4);
        *(float4*)(sls +  0) = t0;
        *(float4*)(sls + 16) = t1;
        *(float4*)(sls + 32) = t2;
        *(float4*)(sls + 48) = t3;
        __syncthreads();

        float av[8] = {a0.x, a0.y, a0.z, a0.w, a1.x, a1.y, a1.z, a1.w};
#pragma unroll
        for (int j = 0; j < 8; ++j) {
            ps += (double)av[j] * wa[kb + j];
            pd += (double)av[j] * wa[D_IN + kb + j];
        }
        s16x8 ah, al;
#pragma unroll
        for (int j = 0; j < 8; ++j) {
            unsigned short h = f2bf(av[j]);
            ah[j] = (short)h;
            al[j] = (short)f2bf(av[j] - bf2f(h));
        }
#pragma unroll
        for (int t = 0; t < 8; ++t) {
            const unsigned char* bp = bsm + (t * 16 + c) * BROW + q * 16;
            s16x8 bh = *(const s16x8*)(bp);
            s16x8 bl = *(const s16x8*)(bp + 64);
            acc[t] = __builtin_amdgcn_mfma_f32_16x16x32_bf16(al, bh, acc[t], 0, 0, 0);
            acc[t] = __builtin_amdgcn_mfma_f32_16x16x32_bf16(ah, bl, acc[t], 0, 0, 0);
            acc[t] = __builtin_amdgcn_mfma_f32_16x16x32_bf16(ah, bh, acc[t], 0, 0, 0);
        }
        __syncthreads();
    }

    ps += __shfl_xor(ps, 16); ps += __shfl_xor(ps, 32);
    pd += __shfl_xor(pd, 16); pd += __shfl_xor(pd, 32);
    if (q == 0 && arow < M) { svec[arow] = ps; dvec[arow] = pd; }

#pragma unroll
    for (int t = 0; t < 8; ++t) {
#pragma unroll
        for (int reg = 0; reg < 4; ++reg) {
            int r = r0 + q * 4 + reg;
            if (r < M) m[(size_t)r * D_OUT + t * 16 + c] = acc[t][reg];
        }
    }
}

// ---------------------------------------------------------------------------
// Dispatch D: fill CSR — NO atomics. Slot = base4[shard][src] + rank (rank
// precomputed in prep_count with identical thread->edge & shard mapping).
// ---------------------------------------------------------------------------
__global__ __launch_bounds__(256) void fill_kernel(
    const int* __restrict__ src, const int* __restrict__ dst,
    const float* __restrict__ nvals, const int* __restrict__ base4,
    const int* __restrict__ rank, int2* __restrict__ edges, int M, int E) {
    const int* bas = base4 + (size_t)(threadIdx.x & 3) * M;
    int base = (blockIdx.x * 256 + (int)threadIdx.x) * 4;
    if (base + 4 <= E) {
        int4   s4 = *(const int4*)(src + base);
        int4   d4 = *(const int4*)(dst + base);
        int4   r4 = *(const int4*)(rank + base);
        float4 n4 = *(const float4*)(nvals + base);
        edges[bas[s4.x] + r4.x] = make_int2(d4.x, __float_as_int(n4.x));
        edges[bas[s4.y] + r4.y] = make_int2(d4.y, __float_as_int(n4.y));
        edges[bas[s4.z] + r4.z] = make_int2(d4.z, __float_as_int(n4.z));
        edges[bas[s4.w] + r4.w] = make_int2(d4.w, __float_as_int(n4.w));
    } else {
        for (int i = base; i < E; ++i)
            edges[bas[src[i]] + rank[i]] = make_int2(dst[i], __float_as_int(nvals[i]));
    }
}

// ---------------------------------------------------------------------------
// Dispatch E: one wave per row. Pass A: fp64 row_sum + cache {dst, nv*v} in
// LDS. Pass B: fp32 m gather (float2/lane) unroll 16. No atomics.
// ---------------------------------------------------------------------------
__global__ __launch_bounds__(256) void row_kernel(
    const int* __restrict__ rowptr, const int2* __restrict__ edges,
    const double* __restrict__ svec, const double* __restrict__ dvec,
    const float* __restrict__ m, float* __restrict__ out, int M) {
    __shared__ int   s_dst[4][CAP];
    __shared__ float s_c[4][CAP];
    int w    = threadIdx.x >> 6;
    int lane = threadIdx.x & 63;
    int r    = blockIdx.x * 4 + w;
    if (r >= M) return;
    int beg = rowptr[r], end = rowptr[r + 1], len = end - beg;
    double sr  = svec[r];
    double sum = 0.0;
    for (int j = lane; j < len; j += 64) {
        int2 ed = edges[beg + j];
        double v = sr + dvec[ed.x];
        v = (v > 0.0) ? v : v * NEG_SLOPE;
        sum += v;
        if (j < CAP) {
            s_dst[w][j] = ed.x;
            s_c[w][j]   = (float)((double)__int_as_float(ed.y) * v);
        }
    }
#pragma unroll
    for (int off = 32; off > 0; off >>= 1) sum += __shfl_xor(sum, off);
    float invf = (float)(1.0 / sum);
    __builtin_amdgcn_wave_barrier();   // order LDS writes (pass A) before reads

    float2 acc = make_float2(0.f, 0.f);
    int lim = len < CAP ? len : CAP;
    int j = 0;
    for (; j + 16 <= lim; j += 16) {
        float2 mv[16]; float c16[16];
#pragma unroll
        for (int k = 0; k < 16; ++k) {
            int d  = s_dst[w][j + k];
            c16[k] = s_c[w][j + k] * invf;
            mv[k]  = ((const float2*)(m + (size_t)d * D_OUT))[lane];
        }
#pragma unroll
        for (int k = 0; k < 16; ++k) {
            acc.x = fmaf(c16[k], mv[k].x, acc.x);
            acc.y = fmaf(c16[k], mv[k].y, acc.y);
        }
    }
    for (; j < lim; ++j) {
        int d = s_dst[w][j];
        float cc = s_c[w][j] * invf;
        float2 mv = ((const float2*)(m + (size_t)d * D_OUT))[lane];
        acc.x = fmaf(cc, mv.x, acc.x);
        acc.y = fmaf(cc, mv.y, acc.y);
    }
    for (; j < len; ++j) {   // overflow (len > CAP): recompute inline
        int2 ed = edges[beg + j];
        double v = sr + dvec[ed.x];
        v = (v > 0.0) ? v : v * NEG_SLOPE;
        float cc = (float)((double)__int_as_float(ed.y) * v) * invf;
        float2 mv = ((const float2*)(m + (size_t)ed.x * D_OUT))[lane];
        acc.x = fmaf(cc, mv.x, acc.x);
        acc.y = fmaf(cc, mv.y, acc.y);
    }
    ((float2*)(out + (size_t)r * D_OUT))[lane] = acc;
}

// ---------------------------------------------------------------------------
extern "C" void kernel_launch(void* const* d_in, const int* in_sizes, int n_in,
                              void* d_out, int out_size, void* d_ws, size_t ws_size,
                              hipStream_t stream) {
    const float* x     = (const float*)d_in[0];
    const float* W     = (const float*)d_in[1];
    const float* a     = (const float*)d_in[2];
    const float* nvals = (const float*)d_in[3];
    const int*   nsrc  = (const int*)d_in[4];
    const int*   ndst  = (const int*)d_in[5];
    const int M = in_sizes[0] / D_IN;   // 50000
    const int E = in_sizes[4];          // 1600000
    float* out = (float*)d_out;

    char* ws = (char*)d_ws;
    size_t off = 0;
    float*  m    = (float*)(ws + off);           off += (size_t)M * D_OUT * sizeof(float); // 25.6 MB
    unsigned short* wth = (unsigned short*)(ws + off); off += (size_t)D_OUT * D_IN * 2;    // 64 KB
    unsigned short* wtl = (unsigned short*)(ws + off); off += (size_t)D_OUT * D_IN * 2;    // 64 KB
    double* wa   = (double*)(ws + off);          off += (size_t)2 * D_IN * sizeof(double); // 4 KB
    double* svec = (double*)(ws + off);          off += (size_t)M * sizeof(double);
    double* dvec = (double*)(ws + off);          off += (size_t)M * sizeof(double);
    int*    counts4 = (int*)(ws + off); off += ((size_t)4 * M * sizeof(int) + 15) & ~15ull; // 800 KB
    int*    base4   = (int*)(ws + off); off += ((size_t)4 * M * sizeof(int) + 15) & ~15ull; // 800 KB
    int*    rowptr  = (int*)(ws + off); off += ((size_t)(M + 1) * sizeof(int) + 15) & ~15ull;
    int*    bsum    = (int*)(ws + off); off += (256 * sizeof(int) + 15) & ~15ull;
    int*    boff    = (int*)(ws + off); off += (256 * sizeof(int) + 15) & ~15ull;
    int*    rank    = (int*)(ws + off); off += (size_t)E * sizeof(int);                     // 6.4 MB
    int2*   edges   = (int2*)(ws + off); off += (size_t)E * sizeof(int2);                   // 12.8 MB

    hipMemsetAsync(counts4, 0, (size_t)4 * M * sizeof(int), stream);

    const int countBlocks = (E + 1023) / 1024;   // 1563
    const int gemmBlocks  = (M + 63) / 64;       // 782
    const int NB          = (M + 255) / 256;     // 196

    prep_count<<<129 + countBlocks, 256, 0, stream>>>(W, a, wa, wth, wtl, nsrc, counts4, rank, M, E);
    scan1<<<NB, 256, 0, stream>>>(counts4, bsum, M);
    scan2<<<1, 256, 0, stream>>>(bsum, boff, rowptr, NB, M);
    scan3<<<NB, 256, 0, stream>>>(counts4, boff, rowptr, base4, M);
    gemm_mfma<<<gemmBlocks, 256, 0, stream>>>(x, wth, wtl, wa, m, svec, dvec, M);
    fill_kernel<<<countBlocks, 256, 0, stream>>>(nsrc, ndst, nvals, base4, rank, edges, M, E);
    row_kernel<<<(M + 3) / 4, 256, 0, stream>>>(rowptr, edges, svec, dvec, m, out, M);
}